// Round 1
// baseline (231.437 us; speedup 1.0000x reference)
//
#include <hip/hip_runtime.h>

// LSTM (B=8192, T=512, H=5) + MLP 5->32->32->5, fp32.
// Decomposition: 5 lanes per batch row (lane j owns hidden unit j),
// 12 rows per 64-wide wave, one wave per block -> 683 blocks.
// Per step: lane computes 4 gate dots (40 FMA), gates, c/h update locally;
// only cross-lane op is the 5-wide h broadcast (ds_bpermute via __shfl).
// x kept in registers via double-buffered 8-step slabs (dwordx4 loads,
// address-identical across the 5-lane group -> coalesced, 84 MB total).

#define LOG2E 1.44269504088896f

__device__ __forceinline__ float fast_sigmoid(float z) {
  float e = __builtin_amdgcn_exp2f(z * -LOG2E);
  return __builtin_amdgcn_rcpf(1.0f + e);
}

__device__ __forceinline__ float fast_tanh(float z) {
  z = fminf(fmaxf(z, -10.0f), 10.0f);   // avoid inf -> NaN in (1-e)/(1+e)
  float e = __builtin_amdgcn_exp2f(z * (-2.0f * LOG2E));
  return (1.0f - e) * __builtin_amdgcn_rcpf(1.0f + e);
}

constexpr int TT = 512;
constexpr int HD = 5;
constexpr int RPB = 12;   // rows per block (per wave)

__device__ __forceinline__ void load_slab(float* dst, const float* xrow, int t0) {
  // 8 steps * 5 floats = 40 floats = 10 float4 (t0 multiple of 8 -> 16B aligned)
  const float4* p4 = (const float4*)(xrow + t0 * HD);
#pragma unroll
  for (int i = 0; i < 10; ++i) {
    float4 v = p4[i];
    dst[i * 4 + 0] = v.x; dst[i * 4 + 1] = v.y;
    dst[i * 4 + 2] = v.z; dst[i * 4 + 3] = v.w;
  }
}

__global__ __launch_bounds__(64) void lstm_mlp_kernel(
    const float* __restrict__ x,   const float* __restrict__ Wih,
    const float* __restrict__ Whh, const float* __restrict__ bih,
    const float* __restrict__ bhh, const float* __restrict__ W1,
    const float* __restrict__ b1,  const float* __restrict__ W2,
    const float* __restrict__ b2,  const float* __restrict__ W3,
    const float* __restrict__ b3,  float* __restrict__ out, int B)
{
  const int lane = threadIdx.x;
  const int grp  = lane / 5;          // row within block
  const int j    = lane - grp * 5;    // hidden unit owned by this lane
  const int row  = blockIdx.x * RPB + grp;

  __shared__ float sbuf1[RPB * 36];
  __shared__ float sbuf2[RPB * 36];

  if (grp >= RPB || row >= B) return;   // no __syncthreads anywhere -> safe

  // ---- per-lane weight slice: rows {j, 5+j, 10+j, 15+j} of W_ih / W_hh ----
  float wi[4][5], wh[4][5], bsum[4];
#pragma unroll
  for (int g = 0; g < 4; ++g) {
#pragma unroll
    for (int k = 0; k < 5; ++k) {
      wi[g][k] = Wih[(g * 5 + j) * 5 + k];
      wh[g][k] = Whh[(g * 5 + j) * 5 + k];
    }
    bsum[g] = bih[g * 5 + j] + bhh[g * 5 + j];
  }

  const float* xrow = x + (size_t)row * (TT * HD);
  const int lanebase = grp * 5;

  float hv[5] = {0.f, 0.f, 0.f, 0.f, 0.f};
  float c = 0.f;
  float xa[40], xb[40];

  load_slab(xa, xrow, 0);

  // one LSTM step; xs indices are compile-time constants after unroll
  auto step = [&](const float* xs, int s) {
    float xv[5];
#pragma unroll
    for (int k = 0; k < 5; ++k) xv[k] = xs[s * 5 + k];
    float z[4];
#pragma unroll
    for (int g = 0; g < 4; ++g) {
      float acc = bsum[g];
#pragma unroll
      for (int k = 0; k < 5; ++k) acc = fmaf(xv[k], wi[g][k], acc);
#pragma unroll
      for (int k = 0; k < 5; ++k) acc = fmaf(hv[k], wh[g][k], acc);
      z[g] = acc;
    }
    float ig = fast_sigmoid(z[0]);
    float fg = fast_sigmoid(z[1]);
    float gg = fast_tanh(z[2]);
    float og = fast_sigmoid(z[3]);
    c = fmaf(fg, c, ig * gg);
    float hj = og * fast_tanh(c);
#pragma unroll
    for (int k = 0; k < 5; ++k) hv[k] = __shfl(hj, lanebase + k, 64);
  };

#pragma unroll 1
  for (int tc = 0; tc < TT; tc += 16) {
    load_slab(xb, xrow, tc + 8);          // always valid: tc+8 <= 504
#pragma unroll
    for (int s = 0; s < 8; ++s) step(xa, s);
    if (tc + 16 < TT) load_slab(xa, xrow, tc + 16);
#pragma unroll
    for (int s = 0; s < 8; ++s) step(xb, s);
  }

  // ---- MLP head: in = h_last + x[:, 511, :] (x_t=511 lives in xb[35..39]) ----
  float in5[5];
#pragma unroll
  for (int k = 0; k < 5; ++k) in5[k] = hv[k] + xb[35 + k];

  // layer1: lane j computes m in {j, j+5, ...} (<32), share via LDS
#pragma unroll
  for (int p = 0; p < 7; ++p) {
    int m = j + 5 * p;
    if (m < 32) {
      float acc = b1[m];
#pragma unroll
      for (int k = 0; k < 5; ++k) acc = fmaf(W1[m * 5 + k], in5[k], acc);
      sbuf1[grp * 36 + m] = fmaxf(acc, 0.f);
    }
  }
  float y1[32];
#pragma unroll
  for (int k = 0; k < 32; ++k) y1[k] = sbuf1[grp * 36 + k];

  // layer2
#pragma unroll
  for (int p = 0; p < 7; ++p) {
    int m = j + 5 * p;
    if (m < 32) {
      float acc = b2[m];
      const float4* w4 = (const float4*)(W2 + m * 32);
#pragma unroll
      for (int k4 = 0; k4 < 8; ++k4) {
        float4 w = w4[k4];
        acc = fmaf(w.x, y1[k4 * 4 + 0], acc);
        acc = fmaf(w.y, y1[k4 * 4 + 1], acc);
        acc = fmaf(w.z, y1[k4 * 4 + 2], acc);
        acc = fmaf(w.w, y1[k4 * 4 + 3], acc);
      }
      sbuf2[grp * 36 + m] = fmaxf(acc, 0.f);
    }
  }
  float y2[32];
#pragma unroll
  for (int k = 0; k < 32; ++k) y2[k] = sbuf2[grp * 36 + k];

  // layer3: every lane has j in 0..4 -> computes out[row*5 + j]
  {
    float acc = b3[j];
    const float4* w4 = (const float4*)(W3 + j * 32);
#pragma unroll
    for (int k4 = 0; k4 < 8; ++k4) {
      float4 w = w4[k4];
      acc = fmaf(w.x, y2[k4 * 4 + 0], acc);
      acc = fmaf(w.y, y2[k4 * 4 + 1], acc);
      acc = fmaf(w.z, y2[k4 * 4 + 2], acc);
      acc = fmaf(w.w, y2[k4 * 4 + 3], acc);
    }
    out[row * 5 + j] = acc;
  }
}

extern "C" void kernel_launch(void* const* d_in, const int* in_sizes, int n_in,
                              void* d_out, int out_size, void* d_ws, size_t ws_size,
                              hipStream_t stream) {
  const float* x   = (const float*)d_in[0];
  const float* Wih = (const float*)d_in[1];
  const float* Whh = (const float*)d_in[2];
  const float* bih = (const float*)d_in[3];
  const float* bhh = (const float*)d_in[4];
  const float* W1  = (const float*)d_in[5];
  const float* b1  = (const float*)d_in[6];
  const float* W2  = (const float*)d_in[7];
  const float* b2  = (const float*)d_in[8];
  const float* W3  = (const float*)d_in[9];
  const float* b3  = (const float*)d_in[10];

  int B = in_sizes[0] / (TT * HD);
  int grid = (B + RPB - 1) / RPB;
  hipLaunchKernelGGL(lstm_mlp_kernel, dim3(grid), dim3(64), 0, stream,
                     x, Wih, Whh, bih, bhh, W1, b1, W2, b2, W3, b3,
                     (float*)d_out, B);
}